// Round 15
// baseline (374.066 us; speedup 1.0000x reference)
//
#include <hip/hip_runtime.h>
#include <hip/hip_bf16.h>

#define NCH 128      // n_agt == n_ctx
#define EB  64       // edges per block (edge kernel: 2 tiles x 32)
#define NB  32       // nodes per block (node kernels)

typedef __attribute__((ext_vector_type(8))) short bf16x8;
typedef __attribute__((ext_vector_type(4))) float f32x4;

__device__ inline unsigned short f2bf(float v) {
    __hip_bfloat16 h = __float2bfloat16(v);
    return __builtin_bit_cast(unsigned short, h);
}
__device__ inline float bf2f(unsigned short u) {
    return __builtin_bit_cast(float, (unsigned int)u << 16);
}

__device__ inline bf16x8 cvt8(const float* __restrict__ p) {
    bf16x8 r;
#pragma unroll
    for (int i = 0; i < 8; ++i) r[i] = (short)f2bf(p[i]);
    return r;
}

template<bool BF>
__device__ inline bf16x8 load_row8(const void* __restrict__ src, int node, int koff) {
    if constexpr (BF)
        return *(const bf16x8*)((const unsigned short*)src + (size_t)node * NCH + koff);
    else
        return cvt8((const float*)src + (size_t)node * NCH + koff);
}

// Packed bf16 atomic add (2 channels per op), gfx940+/gfx950.
__device__ inline void pk_add_bf16(unsigned short* dst, unsigned int packed) {
    unsigned long long a = (unsigned long long)dst;
    asm volatile("global_atomic_pk_add_bf16 %0, %1, off" :: "v"(a), "v"(packed) : "memory");
}

// ---------------------------------------------------------------------------
// Weight conversion / re-layout to bf16 (131072 bf16 = 256 KB):
//  0: Wd2 | 16384: Wq | 32768: Wc1d | 49152: Wc1q | 65536: Wc1x
//  81920: Wc2 | 98304: Wa | 114688: Wl
// ---------------------------------------------------------------------------
__global__ __launch_bounds__(256) void convert_weights_kernel(
    const float* __restrict__ w_d2, const float* __restrict__ w_q,
    const float* __restrict__ w_c1, const float* __restrict__ w_c2,
    const float* __restrict__ w_a,  const float* __restrict__ w_l,
    unsigned short* __restrict__ out)
{
    int i = blockIdx.x * 256 + threadIdx.x;
    if (i >= 131072) return;
    const float* src; int off;
    if      (i < 16384)  { src = w_d2; off = i; }
    else if (i < 32768)  { src = w_q;  off = i - 16384; }
    else if (i < 49152)  { int j = i - 32768; src = w_c1; off = (j >> 7) * 384 + (j & 127); }
    else if (i < 65536)  { int j = i - 49152; src = w_c1; off = (j >> 7) * 384 + 128 + (j & 127); }
    else if (i < 81920)  { int j = i - 65536; src = w_c1; off = (j >> 7) * 384 + 256 + (j & 127); }
    else if (i < 98304)  { src = w_c2; off = i - 81920; }
    else if (i < 114688) { src = w_a;  off = i - 98304; }
    else                 { src = w_l;  off = i - 114688; }
    out[i] = f2bf(src[off]);
}

// ---------------------------------------------------------------------------
// K=128 GEMM step, A from swizzled bf16 LDS tile (32 rows), B = W rows.
// ---------------------------------------------------------------------------
__device__ inline void gemm_k128_lds(const unsigned short* __restrict__ A,
                                     const unsigned short* __restrict__ W,
                                     int lane, int wave, f32x4 (&acc)[2][2])
{
#pragma unroll
    for (int k = 0; k < 4; ++k) {
        const int koff = k * 32 + (lane >> 4) * 8;
        bf16x8 a[2], b[2];
#pragma unroll
        for (int m = 0; m < 2; ++m) {
            int r = m * 16 + (lane & 15);
            int byte = (r * 256 + koff * 2) ^ ((r & 7) << 4);
            a[m] = *(const bf16x8*)((const char*)A + byte);
        }
#pragma unroll
        for (int n = 0; n < 2; ++n) {
            int wr = wave * 32 + n * 16 + (lane & 15);
            b[n] = *(const bf16x8*)(W + (size_t)wr * NCH + koff);
        }
#pragma unroll
        for (int m = 0; m < 2; ++m)
#pragma unroll
            for (int n = 0; n < 2; ++n)
                acc[m][n] = __builtin_amdgcn_mfma_f32_16x16x32_bf16(a[m], b[n], acc[m][n], 0, 0, 0);
    }
}

// Dual-tile GEMM step: B loaded ONCE, applied to tile rows r and r+32.
__device__ inline void gemm_k128_dual(const unsigned short* __restrict__ A,
                                      const unsigned short* __restrict__ W,
                                      int lane, int wave,
                                      f32x4 (&accA)[2][2], f32x4 (&accB)[2][2])
{
#pragma unroll
    for (int k = 0; k < 4; ++k) {
        const int koff = k * 32 + (lane >> 4) * 8;
        bf16x8 b[2];
#pragma unroll
        for (int n = 0; n < 2; ++n) {
            int wr = wave * 32 + n * 16 + (lane & 15);
            b[n] = *(const bf16x8*)(W + (size_t)wr * NCH + koff);
        }
        bf16x8 a0[2], a1[2];
#pragma unroll
        for (int m = 0; m < 2; ++m) {
            int r = m * 16 + (lane & 15);
            a0[m] = *(const bf16x8*)((const char*)A + ((r * 256 + koff * 2) ^ ((r & 7) << 4)));
            int r2 = r + 32;
            a1[m] = *(const bf16x8*)((const char*)A + ((r2 * 256 + koff * 2) ^ ((r2 & 7) << 4)));
        }
#pragma unroll
        for (int m = 0; m < 2; ++m)
#pragma unroll
            for (int n = 0; n < 2; ++n) {
                accA[m][n] = __builtin_amdgcn_mfma_f32_16x16x32_bf16(a0[m], b[n], accA[m][n], 0, 0, 0);
                accB[m][n] = __builtin_amdgcn_mfma_f32_16x16x32_bf16(a1[m], b[n], accB[m][n], 0, 0, 0);
            }
    }
}

// ---------------------------------------------------------------------------
// GN helpers (dual-tile): stats write partials for one 32-row half (roff);
// apply reads stats, normalizes, ReLUs, packs bf16 into swizzled LDS.
// Caller places barriers.
// ---------------------------------------------------------------------------
__device__ inline void gn_stats_half(const f32x4 (&acc)[2][2],
                                     float (*red_s)[4], float (*red_q)[4],
                                     int lane, int wave, int roff)
{
#pragma unroll
    for (int m = 0; m < 2; ++m)
#pragma unroll
        for (int j = 0; j < 4; ++j) {
            float sv = acc[m][0][j] + acc[m][1][j];
            float qv = acc[m][0][j] * acc[m][0][j] + acc[m][1][j] * acc[m][1][j];
#pragma unroll
            for (int off = 1; off < 16; off <<= 1) {
                sv += __shfl_xor(sv, off);
                qv += __shfl_xor(qv, off);
            }
            if ((lane & 15) == 0) {
                int r = roff + m * 16 + (lane >> 4) * 4 + j;
                red_s[r][wave] = sv;
                red_q[r][wave] = qv;
            }
        }
}

__device__ inline void gn_apply_half(const f32x4 (&acc)[2][2],
                                     float (*red_s)[4], float (*red_q)[4],
                                     const float* __restrict__ gamma,
                                     const float* __restrict__ beta,
                                     unsigned short* __restrict__ dst,
                                     int lane, int wave, int roff)
{
    const int c0 = wave * 32 + (lane & 15);
    const float g0 = gamma[c0],      b0 = beta[c0];
    const float g1 = gamma[c0 + 16], b1 = beta[c0 + 16];
#pragma unroll
    for (int m = 0; m < 2; ++m)
#pragma unroll
        for (int j = 0; j < 4; ++j) {
            int r = roff + m * 16 + ((lane >> 4) << 2) + j;
            float4 sv = *(const float4*)red_s[r];
            float4 qv = *(const float4*)red_q[r];
            float ssum = (sv.x + sv.y) + (sv.z + sv.w);
            float qsum = (qv.x + qv.y) + (qv.z + qv.w);
            float mu  = ssum * (1.f / NCH);
            float var = qsum * (1.f / NCH) - mu * mu;
            float rs  = rsqrtf(var + 1e-5f);
            float v0 = fmaxf((acc[m][0][j] - mu) * rs * g0 + b0, 0.f);
            float v1 = fmaxf((acc[m][1][j] - mu) * rs * g1 + b1, 0.f);
            unsigned int p0 = f2bf(v0), p1 = f2bf(v1);
            unsigned int o0 = (unsigned int)__shfl_xor((int)p0, 1);
            unsigned int o1 = (unsigned int)__shfl_xor((int)p1, 1);
            if (!(lane & 1)) {
                int cb = c0 * 2;
                int byte0 = (r * 256 + cb) ^ ((r & 7) << 4);
                int byte1 = (r * 256 + cb + 32) ^ ((r & 7) << 4);
                *(unsigned int*)((char*)dst + byte0) = (p0 & 0xffffu) | (o0 << 16);
                *(unsigned int*)((char*)dst + byte1) = (p1 & 0xffffu) | (o1 << 16);
            }
        }
}

// Normalize + ReLU one 32-row half IN REGISTERS and scatter directly as
// packed-bf16 atomics (the Wc2 GEMM is hoisted to node_post).
__device__ inline void gn_scatter_half(const f32x4 (&acc)[2][2],
                                       float (*red_s)[4], float (*red_q)[4],
                                       const float* __restrict__ gamma,
                                       const float* __restrict__ beta,
                                       const int* __restrict__ sh_h,
                                       unsigned short* __restrict__ out,
                                       int e0, int E, int lane, int wave, int roff)
{
    const int c0 = wave * 32 + (lane & 15);
    const float g0 = gamma[c0],      b0 = beta[c0];
    const float g1 = gamma[c0 + 16], b1 = beta[c0 + 16];
#pragma unroll
    for (int m = 0; m < 2; ++m)
#pragma unroll
        for (int j = 0; j < 4; ++j) {
            int r = roff + m * 16 + ((lane >> 4) << 2) + j;
            float4 sv = *(const float4*)red_s[r];
            float4 qv = *(const float4*)red_q[r];
            float ssum = (sv.x + sv.y) + (sv.z + sv.w);
            float qsum = (qv.x + qv.y) + (qv.z + qv.w);
            float mu  = ssum * (1.f / NCH);
            float var = qsum * (1.f / NCH) - mu * mu;
            float rs  = rsqrtf(var + 1e-5f);
            float v0 = fmaxf((acc[m][0][j] - mu) * rs * g0 + b0, 0.f);
            float v1 = fmaxf((acc[m][1][j] - mu) * rs * g1 + b1, 0.f);
            unsigned int p0 = f2bf(v0), p1 = f2bf(v1);
            unsigned int o0 = (unsigned int)__shfl_xor((int)p0, 1);
            unsigned int o1 = (unsigned int)__shfl_xor((int)p1, 1);
            if (!(lane & 1) && e0 + r < E) {
                unsigned short* rowp = out + (size_t)sh_h[r] * NCH;
                pk_add_bf16(rowp + c0,      (p0 & 0xffffu) | (o0 << 16));
                pk_add_bf16(rowp + c0 + 16, (p1 & 0xffffu) | (o1 << 16));
            }
        }
}

// ---------------------------------------------------------------------------
// N-split GroupNorm stats (node kernels): cross-wave via LDS, one barrier.
// ---------------------------------------------------------------------------
__device__ inline void gn_frag_stats(const f32x4 (&acc)[2][2],
                                     float (*red_s)[4], float (*red_q)[4],
                                     int t, float (&mu)[2][4], float (&rs)[2][4])
{
    const int lane = t & 63, wave = t >> 6;
    gn_stats_half(acc, red_s, red_q, lane, wave, 0);
    __syncthreads();
#pragma unroll
    for (int m = 0; m < 2; ++m)
#pragma unroll
        for (int j = 0; j < 4; ++j) {
            int r = m * 16 + ((lane >> 4) << 2) + j;
            float4 sv = *(const float4*)red_s[r];
            float4 qv = *(const float4*)red_q[r];
            float ssum = (sv.x + sv.y) + (sv.z + sv.w);
            float qsum = (qv.x + qv.y) + (qv.z + qv.w);
            float m_  = ssum * (1.f / NCH);
            float var = qsum * (1.f / NCH) - m_ * m_;
            mu[m][j] = m_;
            rs[m][j] = rsqrtf(var + 1e-5f);
        }
}

__device__ inline void gn_pack_store(const f32x4 (&acc)[2][2],
                                     const float (&mu)[2][4], const float (&rs)[2][4],
                                     const float* __restrict__ gamma,
                                     const float* __restrict__ beta,
                                     unsigned short* __restrict__ dst, int t)
{
    const int lane = t & 63, wave = t >> 6;
    const int c0 = wave * 32 + (lane & 15);
    const float g0 = gamma[c0],      b0 = beta[c0];
    const float g1 = gamma[c0 + 16], b1 = beta[c0 + 16];
#pragma unroll
    for (int m = 0; m < 2; ++m)
#pragma unroll
        for (int j = 0; j < 4; ++j) {
            int r = m * 16 + ((lane >> 4) << 2) + j;
            float v0 = fmaxf((acc[m][0][j] - mu[m][j]) * rs[m][j] * g0 + b0, 0.f);
            float v1 = fmaxf((acc[m][1][j] - mu[m][j]) * rs[m][j] * g1 + b1, 0.f);
            unsigned int p0 = f2bf(v0), p1 = f2bf(v1);
            unsigned int o0 = (unsigned int)__shfl_xor((int)p0, 1);
            unsigned int o1 = (unsigned int)__shfl_xor((int)p1, 1);
            if (!(lane & 1)) {
                int cb = c0 * 2;
                int byte0 = (r * 256 + cb) ^ ((r & 7) << 4);
                int byte1 = (r * 256 + cb + 32) ^ ((r & 7) << 4);
                *(unsigned int*)((char*)dst + byte0) = (p0 & 0xffffu) | (o0 << 16);
                *(unsigned int*)((char*)dst + byte1) = (p1 & 0xffffu) | (o1 << 16);
            }
        }
    __syncthreads();
}

// Pack raw fragments (no GN) as bf16 pairs into a row-major global [N,128] array.
__device__ inline void frag_pack_global(const f32x4 (&acc)[2][2],
                                        unsigned short* __restrict__ dst,
                                        int n0, int N, int t)
{
    const int lane = t & 63, wave = t >> 6;
    const int c0 = wave * 32 + (lane & 15);
#pragma unroll
    for (int m = 0; m < 2; ++m)
#pragma unroll
        for (int j = 0; j < 4; ++j) {
            int r = m * 16 + ((lane >> 4) << 2) + j;
            int ng = n0 + r;
            unsigned int p0 = f2bf(acc[m][0][j]);
            unsigned int p1 = f2bf(acc[m][1][j]);
            unsigned int o0 = (unsigned int)__shfl_xor((int)p0, 1);
            unsigned int o1 = (unsigned int)__shfl_xor((int)p1, 1);
            if (!(lane & 1) && ng < N) {
                unsigned int* rowp = (unsigned int*)(dst + (size_t)ng * NCH);
                rowp[c0 >> 1]        = (p0 & 0xffffu) | (o0 << 16);
                rowp[(c0 + 16) >> 1] = (p1 & 0xffffu) | (o1 << 16);
            }
        }
}

// ---------------------------------------------------------------------------
// node_prep: per 32 nodes — base = agts@Wa^T -> f32 basebuf (d_out);
// q = relu(GN(agts@Wq^T)); pq = q@Wc1q^T (bf16); px = ctx@Wc1x^T (bf16);
// also zeroes this block's rows of c1sum (removes the memset dispatch).
// ---------------------------------------------------------------------------
__global__ __launch_bounds__(256) void node_prep_kernel(
    const float* __restrict__ agts, const float* __restrict__ ctx,
    const unsigned short* __restrict__ wbf,
    const float* __restrict__ g_q, const float* __restrict__ bt_q,
    float* __restrict__ basebuf,
    unsigned short* __restrict__ pq, unsigned short* __restrict__ px,
    unsigned short* __restrict__ c1sum, int N)
{
    const int t = threadIdx.x;
    const int lane = t & 63, wave = t >> 6;
    const int n0 = blockIdx.x * NB;

    __shared__ unsigned short bfQ[NB * NCH];
    __shared__ __align__(16) float red_s[NB][4];
    __shared__ __align__(16) float red_q[NB][4];

    const unsigned short* Wq   = wbf + 16384;
    const unsigned short* Wc1q = wbf + 49152;
    const unsigned short* Wc1x = wbf + 65536;
    const unsigned short* Wa   = wbf + 98304;

    // zero c1sum rows [n0, n0+NB)
    {
        uint4 zz = { 0u, 0u, 0u, 0u };
        int nrows = N - n0; if (nrows > NB) nrows = NB;
        int totalv = nrows * (NCH * 2 / 16);
        uint4* p = (uint4*)(c1sum + (size_t)n0 * NCH);
        for (int i = t; i < totalv; i += 256) p[i] = zz;
    }

    int r0 = n0 + (lane & 15);      if (r0 >= N) r0 = N - 1;
    int r1 = n0 + 16 + (lane & 15); if (r1 >= N) r1 = N - 1;

    const f32x4 z = { 0.f, 0.f, 0.f, 0.f };
    f32x4 accO[2][2] = { { z, z }, { z, z } };
    f32x4 accQ[2][2] = { { z, z }, { z, z } };
#pragma unroll
    for (int k = 0; k < 4; ++k) {
        const int koff = k * 32 + (lane >> 4) * 8;
        bf16x8 a[2], bo[2], bq[2];
        a[0] = load_row8<false>(agts, r0, koff);
        a[1] = load_row8<false>(agts, r1, koff);
#pragma unroll
        for (int n = 0; n < 2; ++n) {
            int wr = wave * 32 + n * 16 + (lane & 15);
            bo[n] = *(const bf16x8*)(Wa + (size_t)wr * NCH + koff);
            bq[n] = *(const bf16x8*)(Wq + (size_t)wr * NCH + koff);
        }
#pragma unroll
        for (int m = 0; m < 2; ++m)
#pragma unroll
            for (int n = 0; n < 2; ++n) {
                accO[m][n] = __builtin_amdgcn_mfma_f32_16x16x32_bf16(a[m], bo[n], accO[m][n], 0, 0, 0);
                accQ[m][n] = __builtin_amdgcn_mfma_f32_16x16x32_bf16(a[m], bq[n], accQ[m][n], 0, 0, 0);
            }
    }
#pragma unroll
    for (int m = 0; m < 2; ++m)
#pragma unroll
        for (int n = 0; n < 2; ++n)
#pragma unroll
            for (int j = 0; j < 4; ++j) {
                int r = m * 16 + ((lane >> 4) << 2) + j;
                int ng = n0 + r;
                if (ng < N)
                    basebuf[(size_t)ng * NCH + wave * 32 + n * 16 + (lane & 15)] = accO[m][n][j];
            }
    float mu[2][4], rs[2][4];
    gn_frag_stats(accQ, red_s, red_q, t, mu, rs);
    gn_pack_store(accQ, mu, rs, g_q, bt_q, bfQ, t);

    f32x4 accPq[2][2] = { { z, z }, { z, z } };
    f32x4 accPx[2][2] = { { z, z }, { z, z } };
#pragma unroll
    for (int k = 0; k < 4; ++k) {
        const int koff = k * 32 + (lane >> 4) * 8;
        bf16x8 aq[2], ax[2], bq2[2], bx[2];
#pragma unroll
        for (int m = 0; m < 2; ++m) {
            int r = m * 16 + (lane & 15);
            int byte = (r * 256 + koff * 2) ^ ((r & 7) << 4);
            aq[m] = *(const bf16x8*)((const char*)bfQ + byte);
        }
        ax[0] = load_row8<false>(ctx, r0, koff);
        ax[1] = load_row8<false>(ctx, r1, koff);
#pragma unroll
        for (int n = 0; n < 2; ++n) {
            int wr = wave * 32 + n * 16 + (lane & 15);
            bq2[n] = *(const bf16x8*)(Wc1q + (size_t)wr * NCH + koff);
            bx[n]  = *(const bf16x8*)(Wc1x + (size_t)wr * NCH + koff);
        }
#pragma unroll
        for (int m = 0; m < 2; ++m)
#pragma unroll
            for (int n = 0; n < 2; ++n) {
                accPq[m][n] = __builtin_amdgcn_mfma_f32_16x16x32_bf16(aq[m], bq2[n], accPq[m][n], 0, 0, 0);
                accPx[m][n] = __builtin_amdgcn_mfma_f32_16x16x32_bf16(ax[m], bx[n], accPx[m][n], 0, 0, 0);
            }
    }
    frag_pack_global(accPq, pq, n0, N, t);
    frag_pack_global(accPx, px, n0, N, t);
}

// ---------------------------------------------------------------------------
// Edge pipeline (pk path), dual-tile N-split, no S LDS tile:
// d1 -> d2(GN) -> c1 = Wc1d@d2 + direct-global(pq[hi]+px[wi]) -> GN+relu in
// regs -> pk-scatter c1.  LDS ~20 KB -> up to 5+ blocks/CU.
// ---------------------------------------------------------------------------
__global__ __launch_bounds__(256) void edge_kernel_pk(
    const unsigned short* __restrict__ pq, const unsigned short* __restrict__ px,
    const float* __restrict__ agt_ctrs, const float* __restrict__ ctx_ctrs,
    const int* __restrict__ hi, const int* __restrict__ wi,
    const float* __restrict__ w_d1, const float* __restrict__ b_d1,
    const float* __restrict__ g_d2, const float* __restrict__ bt_d2,
    const float* __restrict__ g_c1, const float* __restrict__ bt_c1,
    const unsigned short* __restrict__ wbf,
    unsigned short* __restrict__ c1sum, int E)
{
    const int t = threadIdx.x;
    const int lane = t & 63;
    const int wave = t >> 6;
    const int e0 = blockIdx.x * EB;

    __shared__ unsigned short bfD[EB * NCH];       // 16 KB, swizzled bf16
    __shared__ __align__(16) float red_s[EB][4];
    __shared__ __align__(16) float red_q[EB][4];
    __shared__ int   sh_h[EB], sh_w[EB];
    __shared__ float sh_dx[EB], sh_dy[EB];

    const unsigned short* Wd2  = wbf;
    const unsigned short* Wc1d = wbf + 32768;

    if (t < EB) {
        int e = e0 + t; if (e >= E) e = E - 1;
        int h = hi[e], w = wi[e];
        sh_h[t] = h; sh_w[t] = w;
        sh_dx[t] = agt_ctrs[2 * h]     - ctx_ctrs[2 * w];
        sh_dy[t] = agt_ctrs[2 * h + 1] - ctx_ctrs[2 * w + 1];
    }
    __syncthreads();

    // ---- d1 = relu(w_d1 . [dx,dy] + b_d1) -> bfD (64 rows) ----
    {
        const int c = t & 127, rh = t >> 7;
        const float wa = w_d1[2 * c], wb = w_d1[2 * c + 1], bb = b_d1[c];
#pragma unroll
        for (int i = 0; i < 32; ++i) {
            int r = rh * 32 + i;
            float v = fmaxf(fmaf(wa, sh_dx[r], fmaf(wb, sh_dy[r], bb)), 0.f);
            unsigned int pv = f2bf(v);
            unsigned int ov = (unsigned int)__shfl_xor((int)pv, 1);
            if (!(c & 1)) {
                int byte = (r * 256 + c * 2) ^ ((r & 7) << 4);
                *(unsigned int*)((char*)bfD + byte) = (pv & 0xffffu) | (ov << 16);
            }
        }
    }
    __syncthreads();

    const f32x4 z = { 0.f, 0.f, 0.f, 0.f };
    f32x4 accA[2][2], accB[2][2];

    // ================= d2 = relu(GN(d1 @ Wd2^T)) -> bfD =================
    accA[0][0] = z; accA[0][1] = z; accA[1][0] = z; accA[1][1] = z;
    accB[0][0] = z; accB[0][1] = z; accB[1][0] = z; accB[1][1] = z;
    gemm_k128_dual(bfD, Wd2, lane, wave, accA, accB);
    gn_stats_half(accA, red_s, red_q, lane, wave, 0);
    gn_stats_half(accB, red_s, red_q, lane, wave, 32);
    __syncthreads();
    gn_apply_half(accA, red_s, red_q, g_d2, bt_d2, bfD, lane, wave, 0);
    gn_apply_half(accB, red_s, red_q, g_d2, bt_d2, bfD, lane, wave, 32);
    __syncthreads();

    // ======= c1 = Wc1d@d2 + (pq[hi]+px[wi]) ; GN+relu in regs ; scatter ====
    {
        const int c0 = wave * 32 + (lane & 15);
#pragma unroll
        for (int m = 0; m < 2; ++m)
#pragma unroll
            for (int j = 0; j < 4; ++j) {
                int r  = m * 16 + ((lane >> 4) << 2) + j;
                int r2 = r + 32;
                const unsigned short* pqA = pq + (size_t)sh_h[r]  * NCH;
                const unsigned short* pxA = px + (size_t)sh_w[r]  * NCH;
                const unsigned short* pqB = pq + (size_t)sh_h[r2] * NCH;
                const unsigned short* pxB = px + (size_t)sh_w[r2] * NCH;
                accA[m][0][j] = bf2f(pqA[c0])      + bf2f(pxA[c0]);
                accA[m][1][j] = bf2f(pqA[c0 + 16]) + bf2f(pxA[c0 + 16]);
                accB[m][0][j] = bf2f(pqB[c0])      + bf2f(pxB[c0]);
                accB[m][1][j] = bf2f(pqB[c0 + 16]) + bf2f(pxB[c0 + 16]);
            }
    }
    gemm_k128_dual(bfD, Wc1d, lane, wave, accA, accB);
    gn_stats_half(accA, red_s, red_q, lane, wave, 0);
    gn_stats_half(accB, red_s, red_q, lane, wave, 32);
    __syncthreads();
    gn_scatter_half(accA, red_s, red_q, g_c1, bt_c1, sh_h, c1sum, e0, E, lane, wave, 0);
    gn_scatter_half(accB, red_s, red_q, g_c1, bt_c1, sh_h, c1sum, e0, E, lane, wave, 32);
}

// ---------------------------------------------------------------------------
// node_post (pk path): h = base(f32, in dst) + c1sum @ Wc2^T ->
// relu(GN) -> GN(h2 @ Wl^T) -> relu(+res) -> dst (f32, in place).
// ---------------------------------------------------------------------------
__global__ __launch_bounds__(256) void node_post_c2_kernel(
    const unsigned short* __restrict__ c1sum, float* __restrict__ dst,
    const float* __restrict__ agts,
    const float* __restrict__ g_n, const float* __restrict__ bt_n,
    const unsigned short* __restrict__ wc2_bf, const unsigned short* __restrict__ wl_bf,
    const float* __restrict__ g_l, const float* __restrict__ bt_l, int N)
{
    const int t = threadIdx.x;
    const int lane = t & 63, wave = t >> 6;
    const int n0 = blockIdx.x * NB;

    __shared__ unsigned short bfP[NB * NCH];
    __shared__ __align__(16) float red_s[NB][4];
    __shared__ __align__(16) float red_q[NB][4];

    int r0 = n0 + (lane & 15);      if (r0 >= N) r0 = N - 1;
    int r1 = n0 + 16 + (lane & 15); if (r1 >= N) r1 = N - 1;

    const f32x4 z = { 0.f, 0.f, 0.f, 0.f };
    f32x4 acc[2][2] = { { z, z }, { z, z } };
#pragma unroll
    for (int k = 0; k < 4; ++k) {
        const int koff = k * 32 + (lane >> 4) * 8;
        bf16x8 a[2], b[2];
        a[0] = load_row8<true>(c1sum, r0, koff);
        a[1] = load_row8<true>(c1sum, r1, koff);
#pragma unroll
        for (int n = 0; n < 2; ++n) {
            int wr = wave * 32 + n * 16 + (lane & 15);
            b[n] = *(const bf16x8*)(wc2_bf + (size_t)wr * NCH + koff);
        }
#pragma unroll
        for (int m = 0; m < 2; ++m)
#pragma unroll
            for (int n = 0; n < 2; ++n)
                acc[m][n] = __builtin_amdgcn_mfma_f32_16x16x32_bf16(a[m], b[n], acc[m][n], 0, 0, 0);
    }
    // add base (f32, written by node_prep into dst)
#pragma unroll
    for (int m = 0; m < 2; ++m)
#pragma unroll
        for (int n = 0; n < 2; ++n)
#pragma unroll
            for (int j = 0; j < 4; ++j) {
                int r = m * 16 + ((lane >> 4) << 2) + j;
                int ng = n0 + r;
                if (ng < N)
                    acc[m][n][j] += dst[(size_t)ng * NCH + wave * 32 + n * 16 + (lane & 15)];
            }

    float mu[2][4], rs[2][4];
    gn_frag_stats(acc, red_s, red_q, t, mu, rs);
    gn_pack_store(acc, mu, rs, g_n, bt_n, bfP, t);

    f32x4 acc2[2][2] = { { z, z }, { z, z } };
    gemm_k128_lds(bfP, wl_bf, lane, wave, acc2);

    gn_frag_stats(acc2, red_s, red_q, t, mu, rs);
    const int c0 = wave * 32 + (lane & 15);
    const float g0 = g_l[c0],      b0 = bt_l[c0];
    const float g1 = g_l[c0 + 16], b1 = bt_l[c0 + 16];
#pragma unroll
    for (int m = 0; m < 2; ++m)
#pragma unroll
        for (int j = 0; j < 4; ++j) {
            int r = m * 16 + ((lane >> 4) << 2) + j;
            int ng = n0 + r;
            if (ng < N) {
                float v0 = (acc2[m][0][j] - mu[m][j]) * rs[m][j] * g0 + b0;
                float v1 = (acc2[m][1][j] - mu[m][j]) * rs[m][j] * g1 + b1;
                v0 = fmaxf(v0 + agts[(size_t)ng * NCH + c0], 0.f);
                v1 = fmaxf(v1 + agts[(size_t)ng * NCH + c0 + 16], 0.f);
                dst[(size_t)ng * NCH + c0]      = v0;
                dst[(size_t)ng * NCH + c0 + 16] = v1;
            }
        }
}

// ---------------------------------------------------------------------------
// Fallback edge kernel (no workspace): full in-kernel pipeline from f32 inputs.
// ---------------------------------------------------------------------------
__global__ __launch_bounds__(256) void edge_kernel_fb(
    const float* __restrict__ agts, const float* __restrict__ ctx,
    const float* __restrict__ agt_ctrs, const float* __restrict__ ctx_ctrs,
    const int* __restrict__ hi, const int* __restrict__ wi,
    const float* __restrict__ w_d1, const float* __restrict__ b_d1,
    const float* __restrict__ g_d2, const float* __restrict__ bt_d2,
    const float* __restrict__ g_q, const float* __restrict__ bt_q,
    const float* __restrict__ g_c1, const float* __restrict__ bt_c1,
    const unsigned short* __restrict__ wbf,
    float* __restrict__ outbuf, int E)
{
    const int t = threadIdx.x;
    const int lane = t & 63;
    const int wave = t >> 6;
    const int e0 = blockIdx.x * 32;

    __shared__ unsigned short bfQ[32 * NCH];
    __shared__ unsigned short bfD[32 * NCH];
    __shared__ unsigned short bfX[32 * NCH];
    __shared__ __align__(16) float red_s[32][4];
    __shared__ __align__(16) float red_q[32][4];
    __shared__ int   sh_h[32], sh_w[32];
    __shared__ float sh_dx[32], sh_dy[32];

    const unsigned short* Wd2 = wbf;
    const unsigned short* Wq  = wbf + 16384;
    const unsigned short* Wc1d = wbf + 32768;
    const unsigned short* Wc1q = wbf + 49152;
    const unsigned short* Wc1x = wbf + 65536;
    const unsigned short* Wc2 = wbf + 81920;

    if (t < 32) {
        int e = e0 + t; if (e >= E) e = E - 1;
        int h = hi[e], w = wi[e];
        sh_h[t] = h; sh_w[t] = w;
        sh_dx[t] = agt_ctrs[2 * h]     - ctx_ctrs[2 * w];
        sh_dy[t] = agt_ctrs[2 * h + 1] - ctx_ctrs[2 * w + 1];
    }
    __syncthreads();
    {
        const int r  = t >> 3;
        const int cc = t & 7;
        const int h = sh_h[r], w = sh_w[r];
#pragma unroll
        for (int half = 0; half < 2; ++half) {
            int c = cc + half * 8;
            bf16x8 qv = load_row8<false>(agts, h, c * 8);
            bf16x8 xv = load_row8<false>(ctx, w, c * 8);
            int byte = (r * 256 + c * 16) ^ ((r & 7) << 4);
            *(bf16x8*)((char*)bfQ + byte) = qv;
            *(bf16x8*)((char*)bfX + byte) = xv;
        }
    }
    {
        const int c = t & 127, rh = t >> 7;
        const float wa = w_d1[2 * c], wb = w_d1[2 * c + 1], bb = b_d1[c];
#pragma unroll
        for (int i = 0; i < 16; ++i) {
            int r = rh * 16 + i;
            float v = fmaxf(fmaf(wa, sh_dx[r], fmaf(wb, sh_dy[r], bb)), 0.f);
            unsigned int pv = f2bf(v);
            unsigned int ov = (unsigned int)__shfl_xor((int)pv, 1);
            if (!(c & 1)) {
                int byte = (r * 256 + c * 2) ^ ((r & 7) << 4);
                *(unsigned int*)((char*)bfD + byte) = (pv & 0xffffu) | (ov << 16);
            }
        }
    }
    __syncthreads();

    const f32x4 z = { 0.f, 0.f, 0.f, 0.f };
    f32x4 acc[2][2];
    float mu[2][4], rs[2][4];

    acc[0][0] = z; acc[0][1] = z; acc[1][0] = z; acc[1][1] = z;
    gemm_k128_lds(bfD, Wd2, lane, wave, acc);
    gn_frag_stats(acc, red_s, red_q, t, mu, rs);
    gn_pack_store(acc, mu, rs, g_d2, bt_d2, bfD, t);

    acc[0][0] = z; acc[0][1] = z; acc[1][0] = z; acc[1][1] = z;
    gemm_k128_lds(bfQ, Wq, lane, wave, acc);
    gn_frag_stats(acc, red_s, red_q, t, mu, rs);
    gn_pack_store(acc, mu, rs, g_q, bt_q, bfQ, t);

    acc[0][0] = z; acc[0][1] = z; acc[1][0] = z; acc[1][1] = z;
    gemm_k128_lds(bfD, Wc1d, lane, wave, acc);
    gemm_k128_lds(bfQ, Wc1q, lane, wave, acc);
    gemm_k128_lds(bfX, Wc1x, lane, wave, acc);
    gn_frag_stats(acc, red_s, red_q, t, mu, rs);
    gn_pack_store(acc, mu, rs, g_c1, bt_c1, bfD, t);

    acc[0][0] = z; acc[0][1] = z; acc[1][0] = z; acc[1][1] = z;
    gemm_k128_lds(bfD, Wc2, lane, wave, acc);
#pragma unroll
    for (int m = 0; m < 2; ++m)
#pragma unroll
        for (int n = 0; n < 2; ++n)
#pragma unroll
            for (int j = 0; j < 4; ++j) {
                int r = m * 16 + ((lane >> 4) << 2) + j;
                if (e0 + r < E)
                    atomicAdd(&outbuf[(size_t)sh_h[r] * NCH + wave * 32 + n * 16 + (lane & 15)],
                              acc[m][n][j]);
            }
}

// ---------------------------------------------------------------------------
// node_init (fallback only): out = agts @ w_a^T via MFMA.
// ---------------------------------------------------------------------------
__global__ __launch_bounds__(256) void node_init_kernel(
    const float* __restrict__ agts, const unsigned short* __restrict__ wa_bf,
    float* __restrict__ outbuf, int N)
{
    const int t = threadIdx.x;
    const int lane = t & 63, wave = t >> 6;
    const int n0 = blockIdx.x * NB;

    int r0 = n0 + (lane & 15);      if (r0 >= N) r0 = N - 1;
    int r1 = n0 + 16 + (lane & 15); if (r1 >= N) r1 = N - 1;

    const f32x4 z = { 0.f, 0.f, 0.f, 0.f };
    f32x4 acc[2][2] = { { z, z }, { z, z } };
#pragma unroll
    for (int k = 0; k < 4; ++k) {
        const int koff = k * 32 + (lane >> 4) * 8;
        bf16x8 a[2], b[2];
        a[0] = load_row8<false>(agts, r0, koff);
        a[1] = load_row8<false>(agts, r1, koff);
#pragma unroll
        for (int n = 0; n < 2; ++n) {
            int wr = wave * 32 + n * 16 + (lane & 15);
            b[n] = *(const bf16x8*)(wa_bf + (size_t)wr * NCH + koff);
        }
#pragma unroll
        for (int m = 0; m < 2; ++m)
#pragma unroll
            for (int n = 0; n < 2; ++n)
                acc[m][n] = __builtin_amdgcn_mfma_f32_16x16x32_bf16(a[m], b[n], acc[m][n], 0, 0, 0);
    }
#pragma unroll
    for (int m = 0; m < 2; ++m)
#pragma unroll
        for (int n = 0; n < 2; ++n)
#pragma unroll
            for (int j = 0; j < 4; ++j) {
                int r = m * 16 + ((lane >> 4) << 2) + j;
                int ng = n0 + r;
                if (ng < N)
                    outbuf[(size_t)ng * NCH + wave * 32 + n * 16 + (lane & 15)] = acc[m][n][j];
            }
}

// ---------------------------------------------------------------------------
// node_post (fallback): relu(GN(dst)) -> GN(h @ Wl^T) -> relu(+res), in place.
// ---------------------------------------------------------------------------
__global__ __launch_bounds__(256) void node_post_fb_kernel(
    float* __restrict__ dst, const float* __restrict__ agts,
    const float* __restrict__ g_n, const float* __restrict__ bt_n,
    const unsigned short* __restrict__ wl_bf,
    const float* __restrict__ g_l, const float* __restrict__ bt_l, int N)
{
    const int t = threadIdx.x;
    const int lane = t & 63, wave = t >> 6;
    const int n0 = blockIdx.x * NB;

    __shared__ unsigned short bfP[NB * NCH];
    __shared__ __align__(16) float red_s[NB][4];
    __shared__ __align__(16) float red_q[NB][4];

    const int c = t & 127, rh = t >> 7;
    float v[16];
#pragma unroll
    for (int i = 0; i < 16; ++i) {
        int n = n0 + rh * 16 + i; if (n >= N) n = N - 1;
        v[i] = dst[(size_t)n * NCH + c];
    }
#pragma unroll
    for (int i = 0; i < 16; ++i) {
        float s = v[i], q = v[i] * v[i];
        for (int off = 32; off > 0; off >>= 1) {
            s += __shfl_down(s, off);
            q += __shfl_down(q, off);
        }
        if (lane == 0) { red_s[rh * 16 + i][wave & 1] = s; red_q[rh * 16 + i][wave & 1] = q; }
    }
    __syncthreads();
    {
        const float g = g_n[c], b = bt_n[c];
#pragma unroll
        for (int i = 0; i < 16; ++i) {
            int r = rh * 16 + i;
            float s = red_s[r][0] + red_s[r][1];
            float q = red_q[r][0] + red_q[r][1];
            float m_  = s * (1.f / NCH);
            float var = q * (1.f / NCH) - m_ * m_;
            float rrs = rsqrtf(var + 1e-5f);
            float val = fmaxf((v[i] - m_) * rrs * g + b, 0.f);
            unsigned int pv = f2bf(val);
            unsigned int ov = (unsigned int)__shfl_xor((int)pv, 1);
            if (!(c & 1)) {
                int byte = (r * 256 + c * 2) ^ ((r & 7) << 4);
                *(unsigned int*)((char*)bfP + byte) = (pv & 0xffffu) | (ov << 16);
            }
        }
    }
    __syncthreads();

    const f32x4 z = { 0.f, 0.f, 0.f, 0.f };
    f32x4 acc[2][2] = { { z, z }, { z, z } };
    gemm_k128_lds(bfP, wl_bf, lane, wave, acc);

    float mu[2][4], rs[2][4];
    gn_frag_stats(acc, red_s, red_q, t, mu, rs);
    const int c0 = wave * 32 + (lane & 15);
    const float g0 = g_l[c0],      b0 = bt_l[c0];
    const float g1 = g_l[c0 + 16], b1 = bt_l[c0 + 16];
#pragma unroll
    for (int m = 0; m < 2; ++m)
#pragma unroll
        for (int j = 0; j < 4; ++j) {
            int r = m * 16 + ((lane >> 4) << 2) + j;
            int ng = n0 + r;
            if (ng < N) {
                float v0 = (acc[m][0][j] - mu[m][j]) * rs[m][j] * g0 + b0;
                float v1 = (acc[m][1][j] - mu[m][j]) * rs[m][j] * g1 + b1;
                v0 = fmaxf(v0 + agts[(size_t)ng * NCH + c0], 0.f);
                v1 = fmaxf(v1 + agts[(size_t)ng * NCH + c0 + 16], 0.f);
                dst[(size_t)ng * NCH + c0]      = v0;
                dst[(size_t)ng * NCH + c0 + 16] = v1;
            }
        }
}

// ---------------------------------------------------------------------------
extern "C" void kernel_launch(void* const* d_in, const int* in_sizes, int n_in,
                              void* d_out, int out_size, void* d_ws, size_t ws_size,
                              hipStream_t stream) {
    const float* agts     = (const float*)d_in[0];
    const float* ctx      = (const float*)d_in[1];
    const float* agt_ctrs = (const float*)d_in[2];
    const float* ctx_ctrs = (const float*)d_in[3];
    const int*   hi       = (const int*)d_in[4];
    const int*   wi       = (const int*)d_in[5];
    const float* w_d1     = (const float*)d_in[6];
    const float* b_d1     = (const float*)d_in[7];
    const float* w_d2     = (const float*)d_in[8];
    const float* g_d2     = (const float*)d_in[9];
    const float* bt_d2    = (const float*)d_in[10];
    const float* w_q      = (const float*)d_in[11];
    const float* g_q      = (const float*)d_in[12];
    const float* bt_q     = (const float*)d_in[13];
    const float* w_c1     = (const float*)d_in[14];
    const float* g_c1     = (const float*)d_in[15];
    const float* bt_c1    = (const float*)d_in[16];
    const float* w_c2     = (const float*)d_in[17];
    const float* w_a      = (const float*)d_in[18];
    const float* g_n      = (const float*)d_in[19];
    const float* bt_n     = (const float*)d_in[20];
    const float* w_l      = (const float*)d_in[21];
    const float* g_l      = (const float*)d_in[22];
    const float* bt_l     = (const float*)d_in[23];

    const int N = in_sizes[0] / NCH;
    const int E = in_sizes[4];

    float* outf32 = (float*)d_out;                 // base accum + final output

    unsigned short* wbf   = (unsigned short*)d_ws; // 131072 bf16 weights
    unsigned short* pq    = wbf + 131072;          // Wc1q @ q   per node (bf16)
    unsigned short* px    = pq + (size_t)N * NCH;  // Wc1x @ ctx per node (bf16)
    unsigned short* c1sum = px + (size_t)N * NCH;  // bf16 c1 scatter accumulator
    const size_t need_pk = 262144ull + (size_t)N * NCH * 6ull;
    const bool pk = (d_ws != nullptr) && (ws_size >= need_pk);

    const int nb_nodes = (N + NB - 1) / NB;

    convert_weights_kernel<<<512, 256, 0, stream>>>(w_d2, w_q, w_c1, w_c2, w_a, w_l, wbf);

    if (pk) {
        node_prep_kernel<<<nb_nodes, 256, 0, stream>>>(
            agts, ctx, wbf, g_q, bt_q, outf32, pq, px, c1sum, N);
        edge_kernel_pk<<<(E + EB - 1) / EB, 256, 0, stream>>>(
            pq, px, agt_ctrs, ctx_ctrs, hi, wi,
            w_d1, b_d1, g_d2, bt_d2, g_c1, bt_c1,
            wbf, c1sum, E);
        node_post_c2_kernel<<<nb_nodes, 256, 0, stream>>>(
            c1sum, outf32, agts, g_n, bt_n,
            wbf + 81920, wbf + 114688, g_l, bt_l, N);
    } else {
        node_init_kernel<<<nb_nodes, 256, 0, stream>>>(agts, wbf + 98304, outf32, N);
        edge_kernel_fb<<<(E + 31) / 32, 256, 0, stream>>>(
            agts, ctx, agt_ctrs, ctx_ctrs, hi, wi,
            w_d1, b_d1, g_d2, bt_d2, g_q, bt_q, g_c1, bt_c1,
            wbf, outf32, E);
        node_post_fb_kernel<<<nb_nodes, 256, 0, stream>>>(
            outf32, agts, g_n, bt_n, wbf + 114688, g_l, bt_l, N);
    }
}

// Round 16
// 305.034 us; speedup vs baseline: 1.2263x; 1.2263x over previous
//
#include <hip/hip_runtime.h>
#include <hip/hip_bf16.h>

#define NCH 128      // n_agt == n_ctx
#define EB  64       // edges per block (edge kernel: 2 tiles x 32)
#define NB  32       // nodes per block (node kernels)

typedef __attribute__((ext_vector_type(8))) short bf16x8;
typedef __attribute__((ext_vector_type(4))) float f32x4;

__device__ inline unsigned short f2bf(float v) {
    __hip_bfloat16 h = __float2bfloat16(v);
    return __builtin_bit_cast(unsigned short, h);
}
__device__ inline float bf2f(unsigned short u) {
    return __builtin_bit_cast(float, (unsigned int)u << 16);
}

__device__ inline bf16x8 cvt8(const float* __restrict__ p) {
    bf16x8 r;
#pragma unroll
    for (int i = 0; i < 8; ++i) r[i] = (short)f2bf(p[i]);
    return r;
}

template<bool BF>
__device__ inline bf16x8 load_row8(const void* __restrict__ src, int node, int koff) {
    if constexpr (BF)
        return *(const bf16x8*)((const unsigned short*)src + (size_t)node * NCH + koff);
    else
        return cvt8((const float*)src + (size_t)node * NCH + koff);
}

// ---------------------------------------------------------------------------
// Weight conversion / re-layout to bf16 (131072 bf16 = 256 KB):
//  0: Wd2 | 16384: Wq | 32768: Wc1d | 49152: Wc1q | 65536: Wc1x
//  81920: Wc2 | 98304: Wa | 114688: Wl
// ---------------------------------------------------------------------------
__global__ __launch_bounds__(256) void convert_weights_kernel(
    const float* __restrict__ w_d2, const float* __restrict__ w_q,
    const float* __restrict__ w_c1, const float* __restrict__ w_c2,
    const float* __restrict__ w_a,  const float* __restrict__ w_l,
    unsigned short* __restrict__ out)
{
    int i = blockIdx.x * 256 + threadIdx.x;
    if (i >= 131072) return;
    const float* src; int off;
    if      (i < 16384)  { src = w_d2; off = i; }
    else if (i < 32768)  { src = w_q;  off = i - 16384; }
    else if (i < 49152)  { int j = i - 32768; src = w_c1; off = (j >> 7) * 384 + (j & 127); }
    else if (i < 65536)  { int j = i - 49152; src = w_c1; off = (j >> 7) * 384 + 128 + (j & 127); }
    else if (i < 81920)  { int j = i - 65536; src = w_c1; off = (j >> 7) * 384 + 256 + (j & 127); }
    else if (i < 98304)  { src = w_c2; off = i - 81920; }
    else if (i < 114688) { src = w_a;  off = i - 98304; }
    else                 { src = w_l;  off = i - 114688; }
    out[i] = f2bf(src[off]);
}

// ---------------------------------------------------------------------------
// K=128 GEMM step, A from swizzled bf16 LDS tile (32 rows), B = W rows.
// ---------------------------------------------------------------------------
__device__ inline void gemm_k128_lds(const unsigned short* __restrict__ A,
                                     const unsigned short* __restrict__ W,
                                     int lane, int wave, f32x4 (&acc)[2][2])
{
#pragma unroll
    for (int k = 0; k < 4; ++k) {
        const int koff = k * 32 + (lane >> 4) * 8;
        bf16x8 a[2], b[2];
#pragma unroll
        for (int m = 0; m < 2; ++m) {
            int r = m * 16 + (lane & 15);
            int byte = (r * 256 + koff * 2) ^ ((r & 7) << 4);
            a[m] = *(const bf16x8*)((const char*)A + byte);
        }
#pragma unroll
        for (int n = 0; n < 2; ++n) {
            int wr = wave * 32 + n * 16 + (lane & 15);
            b[n] = *(const bf16x8*)(W + (size_t)wr * NCH + koff);
        }
#pragma unroll
        for (int m = 0; m < 2; ++m)
#pragma unroll
            for (int n = 0; n < 2; ++n)
                acc[m][n] = __builtin_amdgcn_mfma_f32_16x16x32_bf16(a[m], b[n], acc[m][n], 0, 0, 0);
    }
}

// Dual-tile GEMM step: B loaded ONCE, applied to tile rows r and r+32.
__device__ inline void gemm_k128_dual(const unsigned short* __restrict__ A,
                                      const unsigned short* __restrict__ W,
                                      int lane, int wave,
                                      f32x4 (&accA)[2][2], f32x4 (&accB)[2][2])
{
#pragma unroll
    for (int k = 0; k < 4; ++k) {
        const int koff = k * 32 + (lane >> 4) * 8;
        bf16x8 b[2];
#pragma unroll
        for (int n = 0; n < 2; ++n) {
            int wr = wave * 32 + n * 16 + (lane & 15);
            b[n] = *(const bf16x8*)(W + (size_t)wr * NCH + koff);
        }
        bf16x8 a0[2], a1[2];
#pragma unroll
        for (int m = 0; m < 2; ++m) {
            int r = m * 16 + (lane & 15);
            a0[m] = *(const bf16x8*)((const char*)A + ((r * 256 + koff * 2) ^ ((r & 7) << 4)));
            int r2 = r + 32;
            a1[m] = *(const bf16x8*)((const char*)A + ((r2 * 256 + koff * 2) ^ ((r2 & 7) << 4)));
        }
#pragma unroll
        for (int m = 0; m < 2; ++m)
#pragma unroll
            for (int n = 0; n < 2; ++n) {
                accA[m][n] = __builtin_amdgcn_mfma_f32_16x16x32_bf16(a0[m], b[n], accA[m][n], 0, 0, 0);
                accB[m][n] = __builtin_amdgcn_mfma_f32_16x16x32_bf16(a1[m], b[n], accB[m][n], 0, 0, 0);
            }
    }
}

// ---------------------------------------------------------------------------
// GN helpers (dual-tile): stats write partials for one 32-row half (roff);
// apply reads stats, normalizes, ReLUs, packs bf16 into swizzled LDS.
// Caller places barriers.
// ---------------------------------------------------------------------------
__device__ inline void gn_stats_half(const f32x4 (&acc)[2][2],
                                     float (*red_s)[4], float (*red_q)[4],
                                     int lane, int wave, int roff)
{
#pragma unroll
    for (int m = 0; m < 2; ++m)
#pragma unroll
        for (int j = 0; j < 4; ++j) {
            float sv = acc[m][0][j] + acc[m][1][j];
            float qv = acc[m][0][j] * acc[m][0][j] + acc[m][1][j] * acc[m][1][j];
#pragma unroll
            for (int off = 1; off < 16; off <<= 1) {
                sv += __shfl_xor(sv, off);
                qv += __shfl_xor(qv, off);
            }
            if ((lane & 15) == 0) {
                int r = roff + m * 16 + (lane >> 4) * 4 + j;
                red_s[r][wave] = sv;
                red_q[r][wave] = qv;
            }
        }
}

__device__ inline void gn_apply_half(const f32x4 (&acc)[2][2],
                                     float (*red_s)[4], float (*red_q)[4],
                                     const float* __restrict__ gamma,
                                     const float* __restrict__ beta,
                                     unsigned short* __restrict__ dst,
                                     int lane, int wave, int roff)
{
    const int c0 = wave * 32 + (lane & 15);
    const float g0 = gamma[c0],      b0 = beta[c0];
    const float g1 = gamma[c0 + 16], b1 = beta[c0 + 16];
#pragma unroll
    for (int m = 0; m < 2; ++m)
#pragma unroll
        for (int j = 0; j < 4; ++j) {
            int r = roff + m * 16 + ((lane >> 4) << 2) + j;
            float4 sv = *(const float4*)red_s[r];
            float4 qv = *(const float4*)red_q[r];
            float ssum = (sv.x + sv.y) + (sv.z + sv.w);
            float qsum = (qv.x + qv.y) + (qv.z + qv.w);
            float mu  = ssum * (1.f / NCH);
            float var = qsum * (1.f / NCH) - mu * mu;
            float rs  = rsqrtf(var + 1e-5f);
            float v0 = fmaxf((acc[m][0][j] - mu) * rs * g0 + b0, 0.f);
            float v1 = fmaxf((acc[m][1][j] - mu) * rs * g1 + b1, 0.f);
            unsigned int p0 = f2bf(v0), p1 = f2bf(v1);
            unsigned int o0 = (unsigned int)__shfl_xor((int)p0, 1);
            unsigned int o1 = (unsigned int)__shfl_xor((int)p1, 1);
            if (!(lane & 1)) {
                int cb = c0 * 2;
                int byte0 = (r * 256 + cb) ^ ((r & 7) << 4);
                int byte1 = (r * 256 + cb + 32) ^ ((r & 7) << 4);
                *(unsigned int*)((char*)dst + byte0) = (p0 & 0xffffu) | (o0 << 16);
                *(unsigned int*)((char*)dst + byte1) = (p1 & 0xffffu) | (o1 << 16);
            }
        }
}

__device__ inline void scatter_half(const f32x4 (&acc)[2][2], const int* __restrict__ sh_h,
                                    float* __restrict__ outbuf, int e0, int E,
                                    int lane, int wave, int roff)
{
#pragma unroll
    for (int m = 0; m < 2; ++m)
#pragma unroll
        for (int n = 0; n < 2; ++n)
#pragma unroll
            for (int j = 0; j < 4; ++j) {
                int r = roff + m * 16 + ((lane >> 4) << 2) + j;
                if (e0 + r < E)
                    atomicAdd(&outbuf[(size_t)sh_h[r] * NCH + wave * 32 + n * 16 + (lane & 15)],
                              acc[m][n][j]);
            }
}

// ---------------------------------------------------------------------------
// N-split GroupNorm stats (node kernels): cross-wave via LDS, one barrier.
// ---------------------------------------------------------------------------
__device__ inline void gn_frag_stats(const f32x4 (&acc)[2][2],
                                     float (*red_s)[4], float (*red_q)[4],
                                     int t, float (&mu)[2][4], float (&rs)[2][4])
{
    const int lane = t & 63, wave = t >> 6;
    gn_stats_half(acc, red_s, red_q, lane, wave, 0);
    __syncthreads();
#pragma unroll
    for (int m = 0; m < 2; ++m)
#pragma unroll
        for (int j = 0; j < 4; ++j) {
            int r = m * 16 + ((lane >> 4) << 2) + j;
            float4 sv = *(const float4*)red_s[r];
            float4 qv = *(const float4*)red_q[r];
            float ssum = (sv.x + sv.y) + (sv.z + sv.w);
            float qsum = (qv.x + qv.y) + (qv.z + qv.w);
            float m_  = ssum * (1.f / NCH);
            float var = qsum * (1.f / NCH) - m_ * m_;
            mu[m][j] = m_;
            rs[m][j] = rsqrtf(var + 1e-5f);
        }
}

__device__ inline void gn_pack_store(const f32x4 (&acc)[2][2],
                                     const float (&mu)[2][4], const float (&rs)[2][4],
                                     const float* __restrict__ gamma,
                                     const float* __restrict__ beta,
                                     unsigned short* __restrict__ dst, int t)
{
    const int lane = t & 63, wave = t >> 6;
    const int c0 = wave * 32 + (lane & 15);
    const float g0 = gamma[c0],      b0 = beta[c0];
    const float g1 = gamma[c0 + 16], b1 = beta[c0 + 16];
#pragma unroll
    for (int m = 0; m < 2; ++m)
#pragma unroll
        for (int j = 0; j < 4; ++j) {
            int r = m * 16 + ((lane >> 4) << 2) + j;
            float v0 = fmaxf((acc[m][0][j] - mu[m][j]) * rs[m][j] * g0 + b0, 0.f);
            float v1 = fmaxf((acc[m][1][j] - mu[m][j]) * rs[m][j] * g1 + b1, 0.f);
            unsigned int p0 = f2bf(v0), p1 = f2bf(v1);
            unsigned int o0 = (unsigned int)__shfl_xor((int)p0, 1);
            unsigned int o1 = (unsigned int)__shfl_xor((int)p1, 1);
            if (!(lane & 1)) {
                int cb = c0 * 2;
                int byte0 = (r * 256 + cb) ^ ((r & 7) << 4);
                int byte1 = (r * 256 + cb + 32) ^ ((r & 7) << 4);
                *(unsigned int*)((char*)dst + byte0) = (p0 & 0xffffu) | (o0 << 16);
                *(unsigned int*)((char*)dst + byte1) = (p1 & 0xffffu) | (o1 << 16);
            }
        }
    __syncthreads();
}

// Pack raw fragments (no GN) as bf16 pairs into a row-major global [N,128] array.
__device__ inline void frag_pack_global(const f32x4 (&acc)[2][2],
                                        unsigned short* __restrict__ dst,
                                        int n0, int N, int t)
{
    const int lane = t & 63, wave = t >> 6;
    const int c0 = wave * 32 + (lane & 15);
#pragma unroll
    for (int m = 0; m < 2; ++m)
#pragma unroll
        for (int j = 0; j < 4; ++j) {
            int r = m * 16 + ((lane >> 4) << 2) + j;
            int ng = n0 + r;
            unsigned int p0 = f2bf(acc[m][0][j]);
            unsigned int p1 = f2bf(acc[m][1][j]);
            unsigned int o0 = (unsigned int)__shfl_xor((int)p0, 1);
            unsigned int o1 = (unsigned int)__shfl_xor((int)p1, 1);
            if (!(lane & 1) && ng < N) {
                unsigned int* rowp = (unsigned int*)(dst + (size_t)ng * NCH);
                rowp[c0 >> 1]        = (p0 & 0xffffu) | (o0 << 16);
                rowp[(c0 + 16) >> 1] = (p1 & 0xffffu) | (o1 << 16);
            }
        }
}

// ---------------------------------------------------------------------------
// node_prep: per 32 nodes — outbuf = agts@Wa^T (f32); q = relu(GN(agts@Wq^T));
// pq = q@Wc1q^T (bf16); px = ctx@Wc1x^T (bf16).
// ---------------------------------------------------------------------------
__global__ __launch_bounds__(256) void node_prep_kernel(
    const float* __restrict__ agts, const float* __restrict__ ctx,
    const unsigned short* __restrict__ wbf,
    const float* __restrict__ g_q, const float* __restrict__ bt_q,
    float* __restrict__ outbuf,
    unsigned short* __restrict__ pq, unsigned short* __restrict__ px, int N)
{
    const int t = threadIdx.x;
    const int lane = t & 63, wave = t >> 6;
    const int n0 = blockIdx.x * NB;

    __shared__ unsigned short bfQ[NB * NCH];
    __shared__ __align__(16) float red_s[NB][4];
    __shared__ __align__(16) float red_q[NB][4];

    const unsigned short* Wq   = wbf + 16384;
    const unsigned short* Wc1q = wbf + 49152;
    const unsigned short* Wc1x = wbf + 65536;
    const unsigned short* Wa   = wbf + 98304;

    int r0 = n0 + (lane & 15);      if (r0 >= N) r0 = N - 1;
    int r1 = n0 + 16 + (lane & 15); if (r1 >= N) r1 = N - 1;

    const f32x4 z = { 0.f, 0.f, 0.f, 0.f };
    f32x4 accO[2][2] = { { z, z }, { z, z } };
    f32x4 accQ[2][2] = { { z, z }, { z, z } };
#pragma unroll
    for (int k = 0; k < 4; ++k) {
        const int koff = k * 32 + (lane >> 4) * 8;
        bf16x8 a[2], bo[2], bq[2];
        a[0] = load_row8<false>(agts, r0, koff);
        a[1] = load_row8<false>(agts, r1, koff);
#pragma unroll
        for (int n = 0; n < 2; ++n) {
            int wr = wave * 32 + n * 16 + (lane & 15);
            bo[n] = *(const bf16x8*)(Wa + (size_t)wr * NCH + koff);
            bq[n] = *(const bf16x8*)(Wq + (size_t)wr * NCH + koff);
        }
#pragma unroll
        for (int m = 0; m < 2; ++m)
#pragma unroll
            for (int n = 0; n < 2; ++n) {
                accO[m][n] = __builtin_amdgcn_mfma_f32_16x16x32_bf16(a[m], bo[n], accO[m][n], 0, 0, 0);
                accQ[m][n] = __builtin_amdgcn_mfma_f32_16x16x32_bf16(a[m], bq[n], accQ[m][n], 0, 0, 0);
            }
    }
#pragma unroll
    for (int m = 0; m < 2; ++m)
#pragma unroll
        for (int n = 0; n < 2; ++n)
#pragma unroll
            for (int j = 0; j < 4; ++j) {
                int r = m * 16 + ((lane >> 4) << 2) + j;
                int ng = n0 + r;
                if (ng < N)
                    outbuf[(size_t)ng * NCH + wave * 32 + n * 16 + (lane & 15)] = accO[m][n][j];
            }
    float mu[2][4], rs[2][4];
    gn_frag_stats(accQ, red_s, red_q, t, mu, rs);
    gn_pack_store(accQ, mu, rs, g_q, bt_q, bfQ, t);

    f32x4 accPq[2][2] = { { z, z }, { z, z } };
    f32x4 accPx[2][2] = { { z, z }, { z, z } };
#pragma unroll
    for (int k = 0; k < 4; ++k) {
        const int koff = k * 32 + (lane >> 4) * 8;
        bf16x8 aq[2], ax[2], bq2[2], bx[2];
#pragma unroll
        for (int m = 0; m < 2; ++m) {
            int r = m * 16 + (lane & 15);
            int byte = (r * 256 + koff * 2) ^ ((r & 7) << 4);
            aq[m] = *(const bf16x8*)((const char*)bfQ + byte);
        }
        ax[0] = load_row8<false>(ctx, r0, koff);
        ax[1] = load_row8<false>(ctx, r1, koff);
#pragma unroll
        for (int n = 0; n < 2; ++n) {
            int wr = wave * 32 + n * 16 + (lane & 15);
            bq2[n] = *(const bf16x8*)(Wc1q + (size_t)wr * NCH + koff);
            bx[n]  = *(const bf16x8*)(Wc1x + (size_t)wr * NCH + koff);
        }
#pragma unroll
        for (int m = 0; m < 2; ++m)
#pragma unroll
            for (int n = 0; n < 2; ++n) {
                accPq[m][n] = __builtin_amdgcn_mfma_f32_16x16x32_bf16(aq[m], bq2[n], accPq[m][n], 0, 0, 0);
                accPx[m][n] = __builtin_amdgcn_mfma_f32_16x16x32_bf16(ax[m], bx[n], accPx[m][n], 0, 0, 0);
            }
    }
    frag_pack_global(accPq, pq, n0, N, t);
    frag_pack_global(accPx, px, n0, N, t);
}

// ---------------------------------------------------------------------------
// Edge pipeline (big path), dual-tile N-split:
// 64 edges/block as two 32-row tiles; B-fragments shared across tiles;
// GN barriers shared across tiles.  d1 -> d2(GN) -> c1 = Wc1d@d2 + S (GN)
// -> c2 -> scatter.
// ---------------------------------------------------------------------------
__global__ __launch_bounds__(256) void edge_kernel_pre(
    const unsigned short* __restrict__ pq, const unsigned short* __restrict__ px,
    const float* __restrict__ agt_ctrs, const float* __restrict__ ctx_ctrs,
    const int* __restrict__ hi, const int* __restrict__ wi,
    const float* __restrict__ w_d1, const float* __restrict__ b_d1,
    const float* __restrict__ g_d2, const float* __restrict__ bt_d2,
    const float* __restrict__ g_c1, const float* __restrict__ bt_c1,
    const unsigned short* __restrict__ wbf,
    float* __restrict__ outbuf, int E)
{
    const int t = threadIdx.x;
    const int lane = t & 63;
    const int wave = t >> 6;
    const int e0 = blockIdx.x * EB;

    __shared__ unsigned short bfD[EB * NCH];       // 16 KB, swizzled bf16
    __shared__ float S[EB][NCH + 4];               // 33 KB f32 pq+px sums
    __shared__ __align__(16) float red_s[EB][4];
    __shared__ __align__(16) float red_q[EB][4];
    __shared__ int   sh_h[EB], sh_w[EB];
    __shared__ float sh_dx[EB], sh_dy[EB];

    const unsigned short* Wd2  = wbf;
    const unsigned short* Wc1d = wbf + 32768;
    const unsigned short* Wc2  = wbf + 81920;

    if (t < EB) {
        int e = e0 + t; if (e >= E) e = E - 1;
        int h = hi[e], w = wi[e];
        sh_h[t] = h; sh_w[t] = w;
        sh_dx[t] = agt_ctrs[2 * h]     - ctx_ctrs[2 * w];
        sh_dy[t] = agt_ctrs[2 * h + 1] - ctx_ctrs[2 * w + 1];
    }
    __syncthreads();

    // ---- stage S = pq[hi]+px[wi] (f32), 64 rows, coalesced 16B chunks ----
    {
        const int r  = t >> 2;         // 0..63
        const int q4 = t & 3;
        const int h = sh_h[r], w = sh_w[r];
#pragma unroll
        for (int i = 0; i < 4; ++i) {
            int c8 = (q4 * 4 + i) * 8;
            bf16x8 aq = load_row8<true>(pq, h, c8);
            bf16x8 ax = load_row8<true>(px, w, c8);
            float4 lo, hi4;
            lo.x = bf2f((unsigned short)aq[0]) + bf2f((unsigned short)ax[0]);
            lo.y = bf2f((unsigned short)aq[1]) + bf2f((unsigned short)ax[1]);
            lo.z = bf2f((unsigned short)aq[2]) + bf2f((unsigned short)ax[2]);
            lo.w = bf2f((unsigned short)aq[3]) + bf2f((unsigned short)ax[3]);
            hi4.x = bf2f((unsigned short)aq[4]) + bf2f((unsigned short)ax[4]);
            hi4.y = bf2f((unsigned short)aq[5]) + bf2f((unsigned short)ax[5]);
            hi4.z = bf2f((unsigned short)aq[6]) + bf2f((unsigned short)ax[6]);
            hi4.w = bf2f((unsigned short)aq[7]) + bf2f((unsigned short)ax[7]);
            *(float4*)&S[r][c8]     = lo;
            *(float4*)&S[r][c8 + 4] = hi4;
        }
    }
    // ---- d1 = relu(w_d1 . [dx,dy] + b_d1) -> bfD (64 rows) ----
    {
        const int c = t & 127, rh = t >> 7;
        const float wa = w_d1[2 * c], wb = w_d1[2 * c + 1], bb = b_d1[c];
#pragma unroll
        for (int i = 0; i < 32; ++i) {
            int r = rh * 32 + i;
            float v = fmaxf(fmaf(wa, sh_dx[r], fmaf(wb, sh_dy[r], bb)), 0.f);
            unsigned int pv = f2bf(v);
            unsigned int ov = (unsigned int)__shfl_xor((int)pv, 1);
            if (!(c & 1)) {
                int byte = (r * 256 + c * 2) ^ ((r & 7) << 4);
                *(unsigned int*)((char*)bfD + byte) = (pv & 0xffffu) | (ov << 16);
            }
        }
    }
    __syncthreads();

    const f32x4 z = { 0.f, 0.f, 0.f, 0.f };
    f32x4 accA[2][2], accB[2][2];

    // ================= d2 = relu(GN(d1 @ Wd2^T)) -> bfD =================
    accA[0][0] = z; accA[0][1] = z; accA[1][0] = z; accA[1][1] = z;
    accB[0][0] = z; accB[0][1] = z; accB[1][0] = z; accB[1][1] = z;
    gemm_k128_dual(bfD, Wd2, lane, wave, accA, accB);
    gn_stats_half(accA, red_s, red_q, lane, wave, 0);
    gn_stats_half(accB, red_s, red_q, lane, wave, 32);
    __syncthreads();
    gn_apply_half(accA, red_s, red_q, g_d2, bt_d2, bfD, lane, wave, 0);
    gn_apply_half(accB, red_s, red_q, g_d2, bt_d2, bfD, lane, wave, 32);
    __syncthreads();

    // ================= c1 = relu(GN(Wc1d@d2 + S)) -> bfD =================
    {
        const int c0 = wave * 32 + (lane & 15);
#pragma unroll
        for (int m = 0; m < 2; ++m)
#pragma unroll
            for (int j = 0; j < 4; ++j) {
                int r = m * 16 + ((lane >> 4) << 2) + j;
                accA[m][0][j] = S[r][c0];      accA[m][1][j] = S[r][c0 + 16];
                accB[m][0][j] = S[r + 32][c0]; accB[m][1][j] = S[r + 32][c0 + 16];
            }
    }
    gemm_k128_dual(bfD, Wc1d, lane, wave, accA, accB);
    gn_stats_half(accA, red_s, red_q, lane, wave, 0);
    gn_stats_half(accB, red_s, red_q, lane, wave, 32);
    __syncthreads();
    gn_apply_half(accA, red_s, red_q, g_c1, bt_c1, bfD, lane, wave, 0);
    gn_apply_half(accB, red_s, red_q, g_c1, bt_c1, bfD, lane, wave, 32);
    __syncthreads();

    // ================= e = c1 @ Wc2^T ; scatter =================
    accA[0][0] = z; accA[0][1] = z; accA[1][0] = z; accA[1][1] = z;
    accB[0][0] = z; accB[0][1] = z; accB[1][0] = z; accB[1][1] = z;
    gemm_k128_dual(bfD, Wc2, lane, wave, accA, accB);
    scatter_half(accA, sh_h, outbuf, e0, E, lane, wave, 0);
    scatter_half(accB, sh_h, outbuf, e0, E, lane, wave, 32);
}

// ---------------------------------------------------------------------------
// Fallback edge kernel (no workspace): full in-kernel pipeline from f32 inputs.
// ---------------------------------------------------------------------------
__global__ __launch_bounds__(256) void edge_kernel_fb(
    const float* __restrict__ agts, const float* __restrict__ ctx,
    const float* __restrict__ agt_ctrs, const float* __restrict__ ctx_ctrs,
    const int* __restrict__ hi, const int* __restrict__ wi,
    const float* __restrict__ w_d1, const float* __restrict__ b_d1,
    const float* __restrict__ g_d2, const float* __restrict__ bt_d2,
    const float* __restrict__ g_q, const float* __restrict__ bt_q,
    const float* __restrict__ g_c1, const float* __restrict__ bt_c1,
    const unsigned short* __restrict__ wbf,
    float* __restrict__ outbuf, int E)
{
    const int t = threadIdx.x;
    const int lane = t & 63;
    const int wave = t >> 6;
    const int e0 = blockIdx.x * 32;

    __shared__ unsigned short bfQ[32 * NCH];
    __shared__ unsigned short bfD[32 * NCH];
    __shared__ unsigned short bfX[32 * NCH];
    __shared__ __align__(16) float red_s[32][4];
    __shared__ __align__(16) float red_q[32][4];
    __shared__ int   sh_h[32], sh_w[32];
    __shared__ float sh_dx[32], sh_dy[32];

    const unsigned short* Wd2 = wbf;
    const unsigned short* Wq  = wbf + 16384;
    const unsigned short* Wc1d = wbf + 32768;
    const unsigned short* Wc1q = wbf + 49152;
    const unsigned short* Wc1x = wbf + 65536;
    const unsigned short* Wc2 = wbf + 81920;

    if (t < 32) {
        int e = e0 + t; if (e >= E) e = E - 1;
        int h = hi[e], w = wi[e];
        sh_h[t] = h; sh_w[t] = w;
        sh_dx[t] = agt_ctrs[2 * h]     - ctx_ctrs[2 * w];
        sh_dy[t] = agt_ctrs[2 * h + 1] - ctx_ctrs[2 * w + 1];
    }
    __syncthreads();
    {
        const int r  = t >> 3;
        const int cc = t & 7;
        const int h = sh_h[r], w = sh_w[r];
#pragma unroll
        for (int half = 0; half < 2; ++half) {
            int c = cc + half * 8;
            bf16x8 qv = load_row8<false>(agts, h, c * 8);
            bf16x8 xv = load_row8<false>(ctx, w, c * 8);
            int byte = (r * 256 + c * 16) ^ ((r & 7) << 4);
            *(bf16x8*)((char*)bfQ + byte) = qv;
            *(bf16x8*)((char*)bfX + byte) = xv;
        }
    }
    {
        const int c = t & 127, rh = t >> 7;
        const float wa = w_d1[2 * c], wb = w_d1[2 * c + 1], bb = b_d1[c];
#pragma unroll
        for (int i = 0; i < 16; ++i) {
            int r = rh * 16 + i;
            float v = fmaxf(fmaf(wa, sh_dx[r], fmaf(wb, sh_dy[r], bb)), 0.f);
            unsigned int pv = f2bf(v);
            unsigned int ov = (unsigned int)__shfl_xor((int)pv, 1);
            if (!(c & 1)) {
                int byte = (r * 256 + c * 2) ^ ((r & 7) << 4);
                *(unsigned int*)((char*)bfD + byte) = (pv & 0xffffu) | (ov << 16);
            }
        }
    }
    __syncthreads();

    const f32x4 z = { 0.f, 0.f, 0.f, 0.f };
    f32x4 acc[2][2];
    float mu[2][4], rs[2][4];

    acc[0][0] = z; acc[0][1] = z; acc[1][0] = z; acc[1][1] = z;
    gemm_k128_lds(bfD, Wd2, lane, wave, acc);
    gn_frag_stats(acc, red_s, red_q, t, mu, rs);
    gn_pack_store(acc, mu, rs, g_d2, bt_d2, bfD, t);

    acc[0][0] = z; acc[0][1] = z; acc[1][0] = z; acc[1][1] = z;
    gemm_k128_lds(bfQ, Wq, lane, wave, acc);
    gn_frag_stats(acc, red_s, red_q, t, mu, rs);
    gn_pack_store(acc, mu, rs, g_q, bt_q, bfQ, t);

    acc[0][0] = z; acc[0][1] = z; acc[1][0] = z; acc[1][1] = z;
    gemm_k128_lds(bfD, Wc1d, lane, wave, acc);
    gemm_k128_lds(bfQ, Wc1q, lane, wave, acc);
    gemm_k128_lds(bfX, Wc1x, lane, wave, acc);
    gn_frag_stats(acc, red_s, red_q, t, mu, rs);
    gn_pack_store(acc, mu, rs, g_c1, bt_c1, bfD, t);

    acc[0][0] = z; acc[0][1] = z; acc[1][0] = z; acc[1][1] = z;
    gemm_k128_lds(bfD, Wc2, lane, wave, acc);
#pragma unroll
    for (int m = 0; m < 2; ++m)
#pragma unroll
        for (int n = 0; n < 2; ++n)
#pragma unroll
            for (int j = 0; j < 4; ++j) {
                int r = m * 16 + ((lane >> 4) << 2) + j;
                if (e0 + r < E)
                    atomicAdd(&outbuf[(size_t)sh_h[r] * NCH + wave * 32 + n * 16 + (lane & 15)],
                              acc[m][n][j]);
            }
}

// ---------------------------------------------------------------------------
// node_init (fallback only): out = agts @ w_a^T via MFMA.
// ---------------------------------------------------------------------------
__global__ __launch_bounds__(256) void node_init_kernel(
    const float* __restrict__ agts, const unsigned short* __restrict__ wa_bf,
    float* __restrict__ outbuf, int N)
{
    const int t = threadIdx.x;
    const int lane = t & 63, wave = t >> 6;
    const int n0 = blockIdx.x * NB;

    int r0 = n0 + (lane & 15);      if (r0 >= N) r0 = N - 1;
    int r1 = n0 + 16 + (lane & 15); if (r1 >= N) r1 = N - 1;

    const f32x4 z = { 0.f, 0.f, 0.f, 0.f };
    f32x4 acc[2][2] = { { z, z }, { z, z } };
#pragma unroll
    for (int k = 0; k < 4; ++k) {
        const int koff = k * 32 + (lane >> 4) * 8;
        bf16x8 a[2], b[2];
        a[0] = load_row8<false>(agts, r0, koff);
        a[1] = load_row8<false>(agts, r1, koff);
#pragma unroll
        for (int n = 0; n < 2; ++n) {
            int wr = wave * 32 + n * 16 + (lane & 15);
            b[n] = *(const bf16x8*)(wa_bf + (size_t)wr * NCH + koff);
        }
#pragma unroll
        for (int m = 0; m < 2; ++m)
#pragma unroll
            for (int n = 0; n < 2; ++n)
                acc[m][n] = __builtin_amdgcn_mfma_f32_16x16x32_bf16(a[m], b[n], acc[m][n], 0, 0, 0);
    }
#pragma unroll
    for (int m = 0; m < 2; ++m)
#pragma unroll
        for (int n = 0; n < 2; ++n)
#pragma unroll
            for (int j = 0; j < 4; ++j) {
                int r = m * 16 + ((lane >> 4) << 2) + j;
                int ng = n0 + r;
                if (ng < N)
                    outbuf[(size_t)ng * NCH + wave * 32 + n * 16 + (lane & 15)] = acc[m][n][j];
            }
}

// ---------------------------------------------------------------------------
// node_post: relu(GN(out)) -> GN(out @ w_l^T) -> relu(+ res), in place, MFMA.
// ---------------------------------------------------------------------------
__global__ __launch_bounds__(256) void node_post_kernel(
    float* __restrict__ outbuf, const float* __restrict__ agts,
    const float* __restrict__ g_n, const float* __restrict__ bt_n,
    const unsigned short* __restrict__ wl_bf,
    const float* __restrict__ g_l, const float* __restrict__ bt_l, int N)
{
    const int t = threadIdx.x;
    const int lane = t & 63, wave = t >> 6;
    const int n0 = blockIdx.x * NB;

    __shared__ unsigned short bfP[NB * NCH];
    __shared__ __align__(16) float red_s[NB][4];
    __shared__ __align__(16) float red_q[NB][4];

    const int c = t & 127, rh = t >> 7;
    float v[16];
#pragma unroll
    for (int i = 0; i < 16; ++i) {
        int n = n0 + rh * 16 + i; if (n >= N) n = N - 1;
        v[i] = outbuf[(size_t)n * NCH + c];
    }
#pragma unroll
    for (int i = 0; i < 16; ++i) {
        float s = v[i], q = v[i] * v[i];
        for (int off = 32; off > 0; off >>= 1) {
            s += __shfl_down(s, off);
            q += __shfl_down(q, off);
        }
        if (lane == 0) { red_s[rh * 16 + i][wave & 1] = s; red_q[rh * 16 + i][wave & 1] = q; }
    }
    __syncthreads();
    {
        const float g = g_n[c], b = bt_n[c];
#pragma unroll
        for (int i = 0; i < 16; ++i) {
            int r = rh * 16 + i;
            float s = red_s[r][0] + red_s[r][1];
            float q = red_q[r][0] + red_q[r][1];
            float m_  = s * (1.f / NCH);
            float var = q * (1.f / NCH) - m_ * m_;
            float rrs = rsqrtf(var + 1e-5f);
            float val = fmaxf((v[i] - m_) * rrs * g + b, 0.f);
            unsigned int pv = f2bf(val);
            unsigned int ov = (unsigned int)__shfl_xor((int)pv, 1);
            if (!(c & 1)) {
                int byte = (r * 256 + c * 2) ^ ((r & 7) << 4);
                *(unsigned int*)((char*)bfP + byte) = (pv & 0xffffu) | (ov << 16);
            }
        }
    }
    __syncthreads();

    const f32x4 z = { 0.f, 0.f, 0.f, 0.f };
    f32x4 acc[2][2] = { { z, z }, { z, z } };
    gemm_k128_lds(bfP, wl_bf, lane, wave, acc);

    float mu[2][4], rs[2][4];
    gn_frag_stats(acc, red_s, red_q, t, mu, rs);
    const int c0 = wave * 32 + (lane & 15);
    const float g0 = g_l[c0],      b0 = bt_l[c0];
    const float g1 = g_l[c0 + 16], b1 = bt_l[c0 + 16];
#pragma unroll
    for (int m = 0; m < 2; ++m)
#pragma unroll
        for (int j = 0; j < 4; ++j) {
            int r = m * 16 + ((lane >> 4) << 2) + j;
            int ng = n0 + r;
            if (ng < N) {
                float v0 = (acc[m][0][j] - mu[m][j]) * rs[m][j] * g0 + b0;
                float v1 = (acc[m][1][j] - mu[m][j]) * rs[m][j] * g1 + b1;
                v0 = fmaxf(v0 + agts[(size_t)ng * NCH + c0], 0.f);
                v1 = fmaxf(v1 + agts[(size_t)ng * NCH + c0 + 16], 0.f);
                outbuf[(size_t)ng * NCH + c0]      = v0;
                outbuf[(size_t)ng * NCH + c0 + 16] = v1;
            }
        }
}

// ---------------------------------------------------------------------------
extern "C" void kernel_launch(void* const* d_in, const int* in_sizes, int n_in,
                              void* d_out, int out_size, void* d_ws, size_t ws_size,
                              hipStream_t stream) {
    const float* agts     = (const float*)d_in[0];
    const float* ctx      = (const float*)d_in[1];
    const float* agt_ctrs = (const float*)d_in[2];
    const float* ctx_ctrs = (const float*)d_in[3];
    const int*   hi       = (const int*)d_in[4];
    const int*   wi       = (const int*)d_in[5];
    const float* w_d1     = (const float*)d_in[6];
    const float* b_d1     = (const float*)d_in[7];
    const float* w_d2     = (const float*)d_in[8];
    const float* g_d2     = (const float*)d_in[9];
    const float* bt_d2    = (const float*)d_in[10];
    const float* w_q      = (const float*)d_in[11];
    const float* g_q      = (const float*)d_in[12];
    const float* bt_q     = (const float*)d_in[13];
    const float* w_c1     = (const float*)d_in[14];
    const float* g_c1     = (const float*)d_in[15];
    const float* bt_c1    = (const float*)d_in[16];
    const float* w_c2     = (const float*)d_in[17];
    const float* w_a      = (const float*)d_in[18];
    const float* g_n      = (const float*)d_in[19];
    const float* bt_n     = (const float*)d_in[20];
    const float* w_l      = (const float*)d_in[21];
    const float* g_l      = (const float*)d_in[22];
    const float* bt_l     = (const float*)d_in[23];

    const int N = in_sizes[0] / NCH;
    const int E = in_sizes[4];

    float* outbuf = (float*)d_out;                 // [N,128] f32 accumulator

    unsigned short* wbf = (unsigned short*)d_ws;   // 131072 bf16 weights
    unsigned short* pq  = wbf + 131072;            // Wc1q @ q   per node (bf16)
    unsigned short* px  = pq + (size_t)N * NCH;    // Wc1x @ ctx per node (bf16)
    const size_t need = 262144ull + (size_t)N * NCH * 4ull;  // bytes
    const bool big = (d_ws != nullptr) && (ws_size >= need);

    const int nb_nodes = (N + NB - 1) / NB;

    convert_weights_kernel<<<512, 256, 0, stream>>>(w_d2, w_q, w_c1, w_c2, w_a, w_l, wbf);

    if (big) {
        node_prep_kernel<<<nb_nodes, 256, 0, stream>>>(
            agts, ctx, wbf, g_q, bt_q, outbuf, pq, px, N);
        edge_kernel_pre<<<(E + EB - 1) / EB, 256, 0, stream>>>(
            pq, px, agt_ctrs, ctx_ctrs, hi, wi,
            w_d1, b_d1, g_d2, bt_d2, g_c1, bt_c1,
            wbf, outbuf, E);
    } else {
        node_init_kernel<<<nb_nodes, 256, 0, stream>>>(agts, wbf + 98304, outbuf, N);
        edge_kernel_fb<<<(E + 31) / 32, 256, 0, stream>>>(
            agts, ctx, agt_ctrs, ctx_ctrs, hi, wi,
            w_d1, b_d1, g_d2, bt_d2, g_q, bt_q, g_c1, bt_c1,
            wbf, outbuf, E);
    }
    node_post_kernel<<<nb_nodes, 256, 0, stream>>>(
        outbuf, agts, g_n, bt_n, wbf + 114688, g_l, bt_l, N);
}